// Round 8
// baseline (170.015 us; speedup 1.0000x reference)
//
#include <hip/hip_runtime.h>

typedef __attribute__((ext_vector_type(8))) short short8;
typedef __attribute__((ext_vector_type(4))) float f32x4;
typedef __attribute__((ext_vector_type(4))) unsigned short u16x4;
typedef __attribute__((ext_vector_type(4))) unsigned int u32x4;

#define MFMA16(A,B,C) __builtin_amdgcn_mfma_f32_16x16x32_bf16(A,B,C,0,0,0)

__device__ __forceinline__ unsigned short f2bf(float f) {
  unsigned int u = __builtin_bit_cast(unsigned int, f);
  unsigned int r = (u + 0x7fffu + ((u >> 16) & 1u)) >> 16;
  return (unsigned short)r;
}

__device__ __forceinline__ unsigned int cvt_pk_bf16(float lo, float hi) {
  unsigned int r;
  asm("v_cvt_pk_bf16_f32 %0, %1, %2" : "=v"(r) : "v"(lo), "v"(hi));
  return r;
}

__device__ __forceinline__ f32x4 zero4() {
  f32x4 z; z.x = 0.f; z.y = 0.f; z.z = 0.f; z.w = 0.f; return z;
}

__device__ __forceinline__ void gl_lds16(const void* g, void* l) {
  __builtin_amdgcn_global_load_lds((const __attribute__((address_space(1))) void*)g,
                                   (__attribute__((address_space(3))) void*)l, 16, 0, 0);
}

// ---------------- prep: f32->bf16 converts + mask bit-pack, one dispatch ----------------
// W_qk q-projection rows pre-scaled by (1/sqrt(hd))*log2(e) -> attn uses exp2 directly.
__global__ __launch_bounds__(256) void prep(const float* __restrict__ xe,
                                            const float* __restrict__ xd,
                                            const float* __restrict__ wqk,
                                            const float* __restrict__ wv,
                                            const float* __restrict__ wo,
                                            const int* __restrict__ mask,
                                            unsigned int* __restrict__ mbits,
                                            unsigned short* __restrict__ ws) {
  if (blockIdx.x >= 12288) {
    int idx = (blockIdx.x - 12288) * 256 + threadIdx.x;   // word index 0..131071
    int row = idx >> 6, wi = idx & 63;
    const int* p = mask + (long)row * 2048 + wi * 32;
    unsigned int bits = 0;
    #pragma unroll
    for (int j = 0; j < 32; j++) bits |= (p[j] != 0 ? 1u : 0u) << j;
    mbits[idx] = bits;
    return;
  }
  long i = (long)blockIdx.x * 256 + threadIdx.x;  // float4 index
  const float* src; unsigned short* dst; long o; bool scl = false;
  if (i < 1048576)      { src = xe;  dst = ws + 8650752;  o = i; }            // xe_bf
  else if (i < 2097152) { src = xd;  dst = ws + 12845056; o = i - 1048576; }  // xd_bf
  else if (i < 2621440) { src = wqk; dst = ws + 17039360; o = i - 2097152;    // wqk_bf
                          scl = (((o >> 8) & 127) < 64); }                    // q rows
  else if (i < 2883584) { src = wv;  dst = ws + 19136512; o = i - 2621440; }  // wv_bf
  else                  { src = wo;  dst = ws + 20185088; o = i - 2883584; }  // wo_bf
  float4 f = ((const float4*)src)[o];
  if (scl) {
    const float SCQ = 0.125f * 1.4426950408889634f;
    f.x *= SCQ; f.y *= SCQ; f.z *= SCQ; f.w *= SCQ;
  }
  u16x4 r; r.x = f2bf(f.x); r.y = f2bf(f.y); r.z = f2bf(f.z); r.w = f2bf(f.w);
  ((u16x4*)dst)[o] = r;
}

// ---------------- fused QK+V GEMM: 768 blocks, K=1024 ----------------
// blocks 0..511:  qk = xe @ wqk^T (4096x2048), bf16 row-major out
// blocks 512..767: v = xd @ wv^T (4096x1024), head-transposed scatter out
__global__ __launch_bounds__(256) void gemm_qkv(const unsigned short* __restrict__ xe,
                                                const unsigned short* __restrict__ xd,
                                                const unsigned short* __restrict__ wqk,
                                                const unsigned short* __restrict__ wv,
                                                unsigned short* __restrict__ qkb,
                                                unsigned short* __restrict__ vTb) {
  __shared__ __align__(16) unsigned short As[128 * 64];
  __shared__ __align__(16) unsigned short Bs[128 * 64];
  const int bid = blockIdx.x;
  const unsigned short* A; const unsigned short* B;
  long row0, col0; int mode;
  if (bid < 512) { A = xe; B = wqk; row0 = (long)(bid >> 4) * 128; col0 = (long)(bid & 15) * 128; mode = 0; }
  else { int id = bid - 512; A = xd; B = wv; row0 = (long)(id >> 3) * 128; col0 = (long)(id & 7) * 128; mode = 1; }

  const int tid = threadIdx.x;
  const int w = tid >> 6, l = tid & 63;
  const int wr = w >> 1, wc = w & 1;
  const int lr = l >> 3;
  const int lc = (l & 7) * 8;

  f32x4 acc[4][4];
  #pragma unroll
  for (int m = 0; m < 4; m++)
    #pragma unroll
    for (int n = 0; n < 4; n++) acc[m][n] = zero4();

  for (int k0 = 0; k0 < 1024; k0 += 64) {
    #pragma unroll
    for (int j = 0; j < 4; j++) {
      int slot = j * 4 + w;
      int row = slot * 8 + lr;
      gl_lds16(A + (row0 + row) * 1024 + k0 + lc, &As[slot * 512]);
      gl_lds16(B + (col0 + row) * 1024 + k0 + lc, &Bs[slot * 512]);
    }
    __syncthreads();
    #pragma unroll
    for (int kk = 0; kk < 2; kk++) {
      short8 a[4], b[4];
      #pragma unroll
      for (int m = 0; m < 4; m++)
        a[m] = *(const short8*)&As[(wr * 64 + m * 16 + (l & 15)) * 64 + kk * 32 + (l >> 4) * 8];
      #pragma unroll
      for (int n = 0; n < 4; n++)
        b[n] = *(const short8*)&Bs[(wc * 64 + n * 16 + (l & 15)) * 64 + kk * 32 + (l >> 4) * 8];
      #pragma unroll
      for (int m = 0; m < 4; m++)
        #pragma unroll
        for (int n = 0; n < 4; n++)
          acc[m][n] = MFMA16(a[m], b[n], acc[m][n]);
    }
    __syncthreads();
  }

  #pragma unroll
  for (int m = 0; m < 4; m++) {
    long rowb = row0 + wr * 64 + m * 16 + ((l >> 4) * 4);
    #pragma unroll
    for (int n = 0; n < 4; n++) {
      long colb = col0 + wc * 64 + n * 16 + (l & 15);
      if (mode == 0) {
        #pragma unroll
        for (int r = 0; r < 4; r++) qkb[(rowb + r) * 2048 + colb] = f2bf(acc[m][n][r]);
      } else {
        long bb = rowb >> 11, s0 = rowb & 2047;
        u16x4 pk;
        pk.x = f2bf(acc[m][n][0]); pk.y = f2bf(acc[m][n][1]);
        pk.z = f2bf(acc[m][n][2]); pk.w = f2bf(acc[m][n][3]);
        *(u16x4*)&vTb[(bb * 1024 + colb) * 2048 + s0] = pk;
      }
    }
  }
}

// ---------------- final GEMM: out = vals @ W_o^T, f32 out ----------------
__global__ __launch_bounds__(256) void gemm_out(const unsigned short* __restrict__ A,
                                                const unsigned short* __restrict__ B,
                                                float* __restrict__ C) {
  __shared__ __align__(16) unsigned short As[128 * 64];
  __shared__ __align__(16) unsigned short Bs[128 * 64];
  const int tid = threadIdx.x;
  const int w = tid >> 6, l = tid & 63;
  const int wr = w >> 1, wc = w & 1;
  const long row0 = (long)blockIdx.y * 128;
  const long col0 = (long)blockIdx.x * 128;
  const int lr = l >> 3;
  const int lc = (l & 7) * 8;

  f32x4 acc[4][4];
  #pragma unroll
  for (int m = 0; m < 4; m++)
    #pragma unroll
    for (int n = 0; n < 4; n++) acc[m][n] = zero4();

  for (int k0 = 0; k0 < 1024; k0 += 64) {
    #pragma unroll
    for (int j = 0; j < 4; j++) {
      int slot = j * 4 + w;
      int row = slot * 8 + lr;
      gl_lds16(A + (row0 + row) * 1024 + k0 + lc, &As[slot * 512]);
      gl_lds16(B + (col0 + row) * 1024 + k0 + lc, &Bs[slot * 512]);
    }
    __syncthreads();
    #pragma unroll
    for (int kk = 0; kk < 2; kk++) {
      short8 a[4], b[4];
      #pragma unroll
      for (int m = 0; m < 4; m++)
        a[m] = *(const short8*)&As[(wr * 64 + m * 16 + (l & 15)) * 64 + kk * 32 + (l >> 4) * 8];
      #pragma unroll
      for (int n = 0; n < 4; n++)
        b[n] = *(const short8*)&Bs[(wc * 64 + n * 16 + (l & 15)) * 64 + kk * 32 + (l >> 4) * 8];
      #pragma unroll
      for (int m = 0; m < 4; m++)
        #pragma unroll
        for (int n = 0; n < 4; n++)
          acc[m][n] = MFMA16(a[m], b[n], acc[m][n]);
    }
    __syncthreads();
  }

  #pragma unroll
  for (int m = 0; m < 4; m++) {
    long rowb = row0 + wr * 64 + m * 16 + ((l >> 4) * 4);
    #pragma unroll
    for (int n = 0; n < 4; n++) {
      long colb = col0 + wc * 64 + n * 16 + (l & 15);
      #pragma unroll
      for (int r = 0; r < 4; r++) C[(rowb + r) * 1024 + colb] = acc[m][n][r];
    }
  }
}

// ---------------- softmax (exp2-direct, masked) + pack + redistribute ----------------
__device__ __forceinline__ void softmax_pack(const f32x4* sf, unsigned long long mw,
                                             int g, int sA, int sB, int gh,
                                             float& l_run, short8& pa0o, short8& pa1o) {
  mw >>= (g * 4);
  unsigned int mlo = (unsigned int)mw, mhi = (unsigned int)(mw >> 32);
  float pv[16];
  float lsum = 0.f;
  #pragma unroll
  for (int kvq = 0; kvq < 4; kvq++) {
    unsigned int msel = (kvq < 2) ? mlo : mhi;
    #pragma unroll
    for (int r = 0; r < 4; r++) {
      float e = __builtin_amdgcn_exp2f(sf[kvq][r]);   // scale pre-folded into W_qk
      unsigned int bit = (msel >> (((kvq & 1) << 4) + r)) & 1u;
      float p = bit ? e : 0.0f;
      pv[kvq * 4 + r] = p;
      lsum += p;
    }
  }
  l_run += lsum;

  unsigned int pk0[2], pk1[2], pk2[2], pk3[2];
  pk0[0] = cvt_pk_bf16(pv[0],  pv[1]);  pk0[1] = cvt_pk_bf16(pv[2],  pv[3]);
  pk1[0] = cvt_pk_bf16(pv[4],  pv[5]);  pk1[1] = cvt_pk_bf16(pv[6],  pv[7]);
  pk2[0] = cvt_pk_bf16(pv[8],  pv[9]);  pk2[1] = cvt_pk_bf16(pv[10], pv[11]);
  pk3[0] = cvt_pk_bf16(pv[12], pv[13]); pk3[1] = cvt_pk_bf16(pv[14], pv[15]);

  u32x4 a0, a1;
  int t0, t1;
  t0 = __shfl((int)pk0[0], sA); t1 = __shfl((int)pk1[0], sA);
  a0.x = gh ? (unsigned)t1 : (unsigned)t0;
  t0 = __shfl((int)pk0[1], sA); t1 = __shfl((int)pk1[1], sA);
  a0.y = gh ? (unsigned)t1 : (unsigned)t0;
  t0 = __shfl((int)pk0[0], sB); t1 = __shfl((int)pk1[0], sB);
  a0.z = gh ? (unsigned)t1 : (unsigned)t0;
  t0 = __shfl((int)pk0[1], sB); t1 = __shfl((int)pk1[1], sB);
  a0.w = gh ? (unsigned)t1 : (unsigned)t0;
  t0 = __shfl((int)pk2[0], sA); t1 = __shfl((int)pk3[0], sA);
  a1.x = gh ? (unsigned)t1 : (unsigned)t0;
  t0 = __shfl((int)pk2[1], sA); t1 = __shfl((int)pk3[1], sA);
  a1.y = gh ? (unsigned)t1 : (unsigned)t0;
  t0 = __shfl((int)pk2[0], sB); t1 = __shfl((int)pk3[0], sB);
  a1.z = gh ? (unsigned)t1 : (unsigned)t0;
  t0 = __shfl((int)pk2[1], sB); t1 = __shfl((int)pk3[1], sB);
  a1.w = gh ? (unsigned)t1 : (unsigned)t0;
  pa0o = __builtin_bit_cast(short8, a0);
  pa1o = __builtin_bit_cast(short8, a1);
}

// ---------------- flash attention: 32 q/wave, K+V LDS dbuf, 4-way KV split ----------------
__global__ __launch_bounds__(256, 4) void attn(const unsigned short* __restrict__ qk,
                                               const unsigned short* __restrict__ vT,
                                               const unsigned int* __restrict__ mbits,
                                               unsigned short* __restrict__ po0,
                                               unsigned short* __restrict__ po1,
                                               unsigned short* __restrict__ po2,
                                               unsigned short* __restrict__ po3,
                                               float* __restrict__ pl0,
                                               float* __restrict__ pl1,
                                               float* __restrict__ pl2,
                                               float* __restrict__ pl3) {
  __shared__ __align__(16) unsigned short Ks[2][64 * 64];
  __shared__ __align__(16) unsigned short Vs[2][64 * 64];
  const int tid = threadIdx.x;
  const int w = tid >> 6, l = tid & 63;
  const int b = blockIdx.z, h = blockIdx.y;
  const int qt = blockIdx.x & 15, kvh = blockIdx.x >> 4;   // kvh 0..3
  const int q0 = qt * 128;
  const int kvbase = kvh << 9;                              // 512-wide KV slices
  unsigned short* po = (kvh == 0) ? po0 : (kvh == 1) ? po1 : (kvh == 2) ? po2 : po3;
  float* pl = (kvh == 0) ? pl0 : (kvh == 1) ? pl1 : (kvh == 2) ? pl2 : pl3;
  const int c = l & 15, g = l >> 4;
  const int lr = l >> 3, pg = l & 7;

  // two q-rows per lane: qa (set A) and qb = qa+16 (set B); Q pre-scaled via W_qk
  const int qa = q0 + w * 32 + c;
  const int qb = qa + 16;
  const unsigned short* qptrA = qk + (long)(b * 2048 + qa) * 2048 + h * 128;
  const unsigned short* qptrB = qk + (long)(b * 2048 + qb) * 2048 + h * 128;
  short8 bqA0 = *(const short8*)&qptrA[g * 8];
  short8 bqA1 = *(const short8*)&qptrA[32 + g * 8];
  short8 bqB0 = *(const short8*)&qptrB[g * 8];
  short8 bqB1 = *(const short8*)&qptrB[32 + g * 8];

  const int sw0 = ((g)     ^ (c & 7)) * 8;
  const int sw1 = ((g + 4) ^ (c & 7)) * 8;
  const int sA = c + (((2 * g)     & 3) << 4);
  const int sB = c + (((2 * g + 1) & 3) << 4);
  const int gh = g >> 1;

  const unsigned int* mrowA = mbits + (long)qa * 64;
  const unsigned int* mrowB = mbits + (long)qb * 64;

  // staging geometry (slot = w + j*4, row = slot*8 + lr, XOR-swizzled source col)
  const unsigned short* kbase = qk + (long)b * 2048 * 2048 + h * 128 + 64;
  const unsigned short* vbase = vT + (long)((b * 16 + h) * 64) * 2048;
  const int srow = w * 8 + lr;
  const int sgg = pg ^ (lr & 7);

  float lA = 0.f, lB = 0.f;
  f32x4 oA[4], oB[4];
  #pragma unroll
  for (int d = 0; d < 4; d++) { oA[d] = zero4(); oB[d] = zero4(); }

  // prologue: stage K,V tile 0 into buf 0
  #pragma unroll
  for (int j = 0; j < 2; j++) {
    int row = srow + j * 32;
    gl_lds16(kbase + (long)(kvbase + row) * 2048 + sgg * 8, &Ks[0][(w + j * 4) * 512]);
    gl_lds16(vbase + (long)row * 2048 + kvbase + sgg * 8,   &Vs[0][(w + j * 4) * 512]);
  }
  __syncthreads();

  for (int it = 0; it < 8; it++) {
    const int kv0 = kvbase + it * 64;
    const int cur = it & 1;

    // issue next tile's staging (async, drained by the end-of-iter barrier)
    if (it < 7) {
      #pragma unroll
      for (int j = 0; j < 2; j++) {
        int row = srow + j * 32;
        gl_lds16(kbase + (long)(kv0 + 64 + row) * 2048 + sgg * 8,
                 &Ks[cur ^ 1][(w + j * 4) * 512]);
        gl_lds16(vbase + (long)row * 2048 + kv0 + 64 + sgg * 8,
                 &Vs[cur ^ 1][(w + j * 4) * 512]);
      }
    }

    unsigned long long mwA = *(const unsigned long long*)&mrowA[kv0 >> 5];
    unsigned long long mwB = *(const unsigned long long*)&mrowB[kv0 >> 5];

    // S^T = K Q^T for both q-sets; K fragments read once from LDS, reused
    f32x4 sfA[4], sfB[4];
    #pragma unroll
    for (int kvq = 0; kvq < 4; kvq++) {
      int R = kvq * 16 + c;
      short8 ak0 = *(const short8*)&Ks[cur][R * 64 + sw0];
      short8 ak1 = *(const short8*)&Ks[cur][R * 64 + sw1];
      f32x4 zA = zero4();
      zA = MFMA16(ak0, bqA0, zA);
      zA = MFMA16(ak1, bqA1, zA);
      sfA[kvq] = zA;
      f32x4 zB = zero4();
      zB = MFMA16(ak0, bqB0, zB);
      zB = MFMA16(ak1, bqB1, zB);
      sfB[kvq] = zB;
    }

    short8 paA0, paA1, paB0, paB1;
    softmax_pack(sfA, mwA, g, sA, sB, gh, lA, paA0, paA1);
    softmax_pack(sfB, mwB, g, sA, sB, gh, lB, paB0, paB1);

    // O += P V ; V fragments read once from LDS, reused across q-sets
    #pragma unroll
    for (int dt = 0; dt < 4; dt++) {
      int d = dt * 16 + c;
      short8 bv0 = *(const short8*)&Vs[cur][d * 64 + sw0];
      short8 bv1 = *(const short8*)&Vs[cur][d * 64 + sw1];
      oA[dt] = MFMA16(paA0, bv0, oA[dt]);
      oA[dt] = MFMA16(paA1, bv1, oA[dt]);
      oB[dt] = MFMA16(paB0, bv0, oB[dt]);
      oB[dt] = MFMA16(paB1, bv1, oB[dt]);
    }

    __syncthreads();
  }

  // l partial reductions + stores for both q-sets
  lA += __shfl_xor(lA, 16); lA += __shfl_xor(lA, 32);
  lB += __shfl_xor(lB, 16); lB += __shfl_xor(lB, 32);
  if (g == 0) {
    pl[((long)(b << 11) + qa) * 16 + h] = lA;
    pl[((long)(b << 11) + qb) * 16 + h] = lB;
  }
  #pragma unroll
  for (int dt = 0; dt < 4; dt++) {
    long rowA = (long)b * 2048 + q0 + w * 32 + g * 4;
    long rowB = rowA + 16;
    int col = h * 64 + dt * 16 + c;
    po[(rowA + 0) * 1024 + col] = f2bf(oA[dt][0]);
    po[(rowA + 1) * 1024 + col] = f2bf(oA[dt][1]);
    po[(rowA + 2) * 1024 + col] = f2bf(oA[dt][2]);
    po[(rowA + 3) * 1024 + col] = f2bf(oA[dt][3]);
    po[(rowB + 0) * 1024 + col] = f2bf(oB[dt][0]);
    po[(rowB + 1) * 1024 + col] = f2bf(oB[dt][1]);
    po[(rowB + 2) * 1024 + col] = f2bf(oB[dt][2]);
    po[(rowB + 3) * 1024 + col] = f2bf(oB[dt][3]);
  }
}

// ---------------- combine 4 KV-split partials: vals = sum(o)/sum(l) ----------------
__global__ __launch_bounds__(256) void combine(const unsigned short* __restrict__ po0,
                                               const unsigned short* __restrict__ po1,
                                               const unsigned short* __restrict__ po2,
                                               const unsigned short* __restrict__ po3,
                                               const float* __restrict__ pl0,
                                               const float* __restrict__ pl1,
                                               const float* __restrict__ pl2,
                                               const float* __restrict__ pl3,
                                               unsigned short* __restrict__ vals) {
  int i = blockIdx.x * 256 + threadIdx.x;   // 0..524287, 8 cols each
  int q = i >> 7;                           // 0..4095 (b*2048+s)
  int col = (i & 127) * 8;
  int h = col >> 6;
  float linv = 1.0f / (pl0[q * 16 + h] + pl1[q * 16 + h] + pl2[q * 16 + h] + pl3[q * 16 + h]);
  long off = (long)q * 1024 + col;
  short8 a = *(const short8*)&po0[off];
  short8 b = *(const short8*)&po1[off];
  short8 cc = *(const short8*)&po2[off];
  short8 d = *(const short8*)&po3[off];
  short8 o;
  #pragma unroll
  for (int j = 0; j < 8; j++) {
    float fa = __builtin_bit_cast(float, ((unsigned int)(unsigned short)a[j]) << 16);
    float fb = __builtin_bit_cast(float, ((unsigned int)(unsigned short)b[j]) << 16);
    float fc = __builtin_bit_cast(float, ((unsigned int)(unsigned short)cc[j]) << 16);
    float fd = __builtin_bit_cast(float, ((unsigned int)(unsigned short)d[j]) << 16);
    o[j] = (short)f2bf((fa + fb + fc + fd) * linv);
  }
  *(short8*)&vals[off] = o;
}

extern "C" void kernel_launch(void* const* d_in, const int* in_sizes, int n_in,
                              void* d_out, int out_size, void* d_ws, size_t ws_size,
                              hipStream_t stream) {
  const float* xe  = (const float*)d_in[0];
  const float* xd  = (const float*)d_in[1];
  const int*   msk = (const int*)d_in[2];
  const float* wqk = (const float*)d_in[3];
  const float* wv  = (const float*)d_in[4];
  const float* wo  = (const float*)d_in[5];
  float* out = (float*)d_out;
  unsigned short* ws = (unsigned short*)d_ws;

  // workspace layout (ushort elements) — same 76.5 MB footprint as R7:
  // [0, 4194304)            po0      | [4194304, 8388608)   po1
  // [8388608, 8519680)      pl0 f32  | [8519680, 8650752)   pl1 f32
  // [8650752, 12845056)     xe_bf    (reused as po2 by attn)
  // [12845056, 17039360)    xd_bf    (reused as po3 by attn)
  // [17039360, 19136512)    wqk_bf   (reused as pl2|pl3 by attn)
  // [19136512, 20185088)    wv_bf    | [20185088, 21233664) wo_bf
  // [21233664, 29622272)    qkb      | [29622272, 33816576) vTb
  // [33816576, 38010880)    valb     | [38010880, 38273024) mbits u32
  unsigned short* po0    = ws;
  unsigned short* po1    = ws + 4194304;
  float*          pl0    = (float*)(ws + 8388608);
  float*          pl1    = (float*)(ws + 8519680);
  unsigned short* xe_bf  = ws + 8650752;
  unsigned short* xd_bf  = ws + 12845056;
  unsigned short* wqk_bf = ws + 17039360;
  unsigned short* wv_bf  = ws + 19136512;
  unsigned short* wo_bf  = ws + 20185088;
  unsigned short* qkb    = ws + 21233664;
  unsigned short* vTb    = ws + 29622272;
  unsigned short* valb   = ws + 33816576;
  unsigned int*   mbits  = (unsigned int*)(ws + 38010880);
  unsigned short* po2    = xe_bf;                       // dead after gemm_qkv
  unsigned short* po3    = xd_bf;                       // dead after gemm_qkv
  float*          pl2    = (float*)wqk_bf;              // dead after gemm_qkv
  float*          pl3    = (float*)(wqk_bf + 131072);

  prep<<<12800, 256, 0, stream>>>(xe, xd, wqk, wv, wo, msk, mbits, ws);
  gemm_qkv<<<768, 256, 0, stream>>>(xe_bf, xd_bf, wqk_bf, wv_bf, qkb, vTb);
  attn<<<dim3(64, 16, 2), 256, 0, stream>>>(qkb, vTb, mbits,
                                            po0, po1, po2, po3, pl0, pl1, pl2, pl3);
  combine<<<2048, 256, 0, stream>>>(po0, po1, po2, po3, pl0, pl1, pl2, pl3, valb);
  gemm_out<<<dim3(8, 32), 256, 0, stream>>>(valb, wo_bf, out);
}

// Round 9
// 169.563 us; speedup vs baseline: 1.0027x; 1.0027x over previous
//
#include <hip/hip_runtime.h>

typedef __attribute__((ext_vector_type(8))) short short8;
typedef __attribute__((ext_vector_type(4))) float f32x4;
typedef __attribute__((ext_vector_type(4))) unsigned short u16x4;
typedef __attribute__((ext_vector_type(4))) unsigned int u32x4;

#define MFMA16(A,B,C) __builtin_amdgcn_mfma_f32_16x16x32_bf16(A,B,C,0,0,0)

__device__ __forceinline__ unsigned short f2bf(float f) {
  unsigned int u = __builtin_bit_cast(unsigned int, f);
  unsigned int r = (u + 0x7fffu + ((u >> 16) & 1u)) >> 16;
  return (unsigned short)r;
}

__device__ __forceinline__ unsigned int cvt_pk_bf16(float lo, float hi) {
  unsigned int r;
  asm("v_cvt_pk_bf16_f32 %0, %1, %2" : "=v"(r) : "v"(lo), "v"(hi));
  return r;
}

__device__ __forceinline__ f32x4 zero4() {
  f32x4 z; z.x = 0.f; z.y = 0.f; z.z = 0.f; z.w = 0.f; return z;
}

__device__ __forceinline__ void gl_lds16(const void* g, void* l) {
  __builtin_amdgcn_global_load_lds((const __attribute__((address_space(1))) void*)g,
                                   (__attribute__((address_space(3))) void*)l, 16, 0, 0);
}

// ---------------- prep: f32->bf16 converts + mask bit-pack, one dispatch ----------------
// W_qk q-projection rows pre-scaled by (1/sqrt(hd))*log2(e) -> attn uses exp2 directly.
__global__ __launch_bounds__(256) void prep(const float* __restrict__ xe,
                                            const float* __restrict__ xd,
                                            const float* __restrict__ wqk,
                                            const float* __restrict__ wv,
                                            const float* __restrict__ wo,
                                            const int* __restrict__ mask,
                                            unsigned int* __restrict__ mbits,
                                            unsigned short* __restrict__ ws) {
  if (blockIdx.x >= 12288) {
    int idx = (blockIdx.x - 12288) * 256 + threadIdx.x;   // word index 0..131071
    int row = idx >> 6, wi = idx & 63;
    const int* p = mask + (long)row * 2048 + wi * 32;
    unsigned int bits = 0;
    #pragma unroll
    for (int j = 0; j < 32; j++) bits |= (p[j] != 0 ? 1u : 0u) << j;
    mbits[idx] = bits;
    return;
  }
  long i = (long)blockIdx.x * 256 + threadIdx.x;  // float4 index
  const float* src; unsigned short* dst; long o; bool scl = false;
  if (i < 1048576)      { src = xe;  dst = ws + 8650752;  o = i; }            // xe_bf
  else if (i < 2097152) { src = xd;  dst = ws + 12845056; o = i - 1048576; }  // xd_bf
  else if (i < 2621440) { src = wqk; dst = ws + 17039360; o = i - 2097152;    // wqk_bf
                          scl = (((o >> 8) & 127) < 64); }                    // q rows
  else if (i < 2883584) { src = wv;  dst = ws + 19136512; o = i - 2621440; }  // wv_bf
  else                  { src = wo;  dst = ws + 20185088; o = i - 2883584; }  // wo_bf
  float4 f = ((const float4*)src)[o];
  if (scl) {
    const float SCQ = 0.125f * 1.4426950408889634f;
    f.x *= SCQ; f.y *= SCQ; f.z *= SCQ; f.w *= SCQ;
  }
  u16x4 r; r.x = f2bf(f.x); r.y = f2bf(f.y); r.z = f2bf(f.z); r.w = f2bf(f.w);
  ((u16x4*)dst)[o] = r;
}

// ---------------- fused QK+V GEMM: 768 blocks, K=1024 ----------------
__global__ __launch_bounds__(256) void gemm_qkv(const unsigned short* __restrict__ xe,
                                                const unsigned short* __restrict__ xd,
                                                const unsigned short* __restrict__ wqk,
                                                const unsigned short* __restrict__ wv,
                                                unsigned short* __restrict__ qkb,
                                                unsigned short* __restrict__ vTb) {
  __shared__ __align__(16) unsigned short As[128 * 64];
  __shared__ __align__(16) unsigned short Bs[128 * 64];
  const int bid = blockIdx.x;
  const unsigned short* A; const unsigned short* B;
  long row0, col0; int mode;
  if (bid < 512) { A = xe; B = wqk; row0 = (long)(bid >> 4) * 128; col0 = (long)(bid & 15) * 128; mode = 0; }
  else { int id = bid - 512; A = xd; B = wv; row0 = (long)(id >> 3) * 128; col0 = (long)(id & 7) * 128; mode = 1; }

  const int tid = threadIdx.x;
  const int w = tid >> 6, l = tid & 63;
  const int wr = w >> 1, wc = w & 1;
  const int lr = l >> 3;
  const int lc = (l & 7) * 8;

  f32x4 acc[4][4];
  #pragma unroll
  for (int m = 0; m < 4; m++)
    #pragma unroll
    for (int n = 0; n < 4; n++) acc[m][n] = zero4();

  for (int k0 = 0; k0 < 1024; k0 += 64) {
    #pragma unroll
    for (int j = 0; j < 4; j++) {
      int slot = j * 4 + w;
      int row = slot * 8 + lr;
      gl_lds16(A + (row0 + row) * 1024 + k0 + lc, &As[slot * 512]);
      gl_lds16(B + (col0 + row) * 1024 + k0 + lc, &Bs[slot * 512]);
    }
    __syncthreads();
    #pragma unroll
    for (int kk = 0; kk < 2; kk++) {
      short8 a[4], b[4];
      #pragma unroll
      for (int m = 0; m < 4; m++)
        a[m] = *(const short8*)&As[(wr * 64 + m * 16 + (l & 15)) * 64 + kk * 32 + (l >> 4) * 8];
      #pragma unroll
      for (int n = 0; n < 4; n++)
        b[n] = *(const short8*)&Bs[(wc * 64 + n * 16 + (l & 15)) * 64 + kk * 32 + (l >> 4) * 8];
      #pragma unroll
      for (int m = 0; m < 4; m++)
        #pragma unroll
        for (int n = 0; n < 4; n++)
          acc[m][n] = MFMA16(a[m], b[n], acc[m][n]);
    }
    __syncthreads();
  }

  #pragma unroll
  for (int m = 0; m < 4; m++) {
    long rowb = row0 + wr * 64 + m * 16 + ((l >> 4) * 4);
    #pragma unroll
    for (int n = 0; n < 4; n++) {
      long colb = col0 + wc * 64 + n * 16 + (l & 15);
      if (mode == 0) {
        #pragma unroll
        for (int r = 0; r < 4; r++) qkb[(rowb + r) * 2048 + colb] = f2bf(acc[m][n][r]);
      } else {
        long bb = rowb >> 11, s0 = rowb & 2047;
        u16x4 pk;
        pk.x = f2bf(acc[m][n][0]); pk.y = f2bf(acc[m][n][1]);
        pk.z = f2bf(acc[m][n][2]); pk.w = f2bf(acc[m][n][3]);
        *(u16x4*)&vTb[(bb * 1024 + colb) * 2048 + s0] = pk;
      }
    }
  }
}

// ---------------- final GEMM: out = vals @ W_o^T, f32 out, 128x64 tiles ----------------
__global__ __launch_bounds__(256) void gemm_out(const unsigned short* __restrict__ A,
                                                const unsigned short* __restrict__ B,
                                                float* __restrict__ C) {
  __shared__ __align__(16) unsigned short As[128 * 64];
  __shared__ __align__(16) unsigned short Bs[64 * 64];
  const int tid = threadIdx.x;
  const int w = tid >> 6, l = tid & 63;
  const int wr = w >> 1, wc = w & 1;
  const long row0 = (long)blockIdx.y * 128;
  const long col0 = (long)blockIdx.x * 64;
  const int lr = l >> 3;
  const int lc = (l & 7) * 8;

  f32x4 acc[4][2];
  #pragma unroll
  for (int m = 0; m < 4; m++)
    #pragma unroll
    for (int n = 0; n < 2; n++) acc[m][n] = zero4();

  for (int k0 = 0; k0 < 1024; k0 += 64) {
    #pragma unroll
    for (int j = 0; j < 4; j++) {
      int slot = j * 4 + w;
      int row = slot * 8 + lr;
      gl_lds16(A + (row0 + row) * 1024 + k0 + lc, &As[slot * 512]);
    }
    #pragma unroll
    for (int j = 0; j < 2; j++) {
      int slot = j * 4 + w;
      int row = slot * 8 + lr;
      gl_lds16(B + (col0 + row) * 1024 + k0 + lc, &Bs[slot * 512]);
    }
    __syncthreads();
    #pragma unroll
    for (int kk = 0; kk < 2; kk++) {
      short8 a[4], b[2];
      #pragma unroll
      for (int m = 0; m < 4; m++)
        a[m] = *(const short8*)&As[(wr * 64 + m * 16 + (l & 15)) * 64 + kk * 32 + (l >> 4) * 8];
      #pragma unroll
      for (int n = 0; n < 2; n++)
        b[n] = *(const short8*)&Bs[(wc * 32 + n * 16 + (l & 15)) * 64 + kk * 32 + (l >> 4) * 8];
      #pragma unroll
      for (int m = 0; m < 4; m++)
        #pragma unroll
        for (int n = 0; n < 2; n++)
          acc[m][n] = MFMA16(a[m], b[n], acc[m][n]);
    }
    __syncthreads();
  }

  #pragma unroll
  for (int m = 0; m < 4; m++) {
    long rowb = row0 + wr * 64 + m * 16 + ((l >> 4) * 4);
    #pragma unroll
    for (int n = 0; n < 2; n++) {
      long colb = col0 + wc * 32 + n * 16 + (l & 15);
      #pragma unroll
      for (int r = 0; r < 4; r++) C[(rowb + r) * 1024 + colb] = acc[m][n][r];
    }
  }
}

// ---------------- softmax (exp2-direct, masked) + pack + redistribute ----------------
__device__ __forceinline__ void softmax_pack(const f32x4* sf, unsigned long long mw,
                                             int g, int sA, int sB, int gh,
                                             float& l_run, short8& pa0o, short8& pa1o) {
  mw >>= (g * 4);
  unsigned int mlo = (unsigned int)mw, mhi = (unsigned int)(mw >> 32);
  float pv[16];
  float lsum = 0.f;
  #pragma unroll
  for (int kvq = 0; kvq < 4; kvq++) {
    unsigned int msel = (kvq < 2) ? mlo : mhi;
    #pragma unroll
    for (int r = 0; r < 4; r++) {
      float e = __builtin_amdgcn_exp2f(sf[kvq][r]);   // scale pre-folded into W_qk
      unsigned int bit = (msel >> (((kvq & 1) << 4) + r)) & 1u;
      float p = bit ? e : 0.0f;
      pv[kvq * 4 + r] = p;
      lsum += p;
    }
  }
  l_run += lsum;

  unsigned int pk0[2], pk1[2], pk2[2], pk3[2];
  pk0[0] = cvt_pk_bf16(pv[0],  pv[1]);  pk0[1] = cvt_pk_bf16(pv[2],  pv[3]);
  pk1[0] = cvt_pk_bf16(pv[4],  pv[5]);  pk1[1] = cvt_pk_bf16(pv[6],  pv[7]);
  pk2[0] = cvt_pk_bf16(pv[8],  pv[9]);  pk2[1] = cvt_pk_bf16(pv[10], pv[11]);
  pk3[0] = cvt_pk_bf16(pv[12], pv[13]); pk3[1] = cvt_pk_bf16(pv[14], pv[15]);

  u32x4 a0, a1;
  int t0, t1;
  t0 = __shfl((int)pk0[0], sA); t1 = __shfl((int)pk1[0], sA);
  a0.x = gh ? (unsigned)t1 : (unsigned)t0;
  t0 = __shfl((int)pk0[1], sA); t1 = __shfl((int)pk1[1], sA);
  a0.y = gh ? (unsigned)t1 : (unsigned)t0;
  t0 = __shfl((int)pk0[0], sB); t1 = __shfl((int)pk1[0], sB);
  a0.z = gh ? (unsigned)t1 : (unsigned)t0;
  t0 = __shfl((int)pk0[1], sB); t1 = __shfl((int)pk1[1], sB);
  a0.w = gh ? (unsigned)t1 : (unsigned)t0;
  t0 = __shfl((int)pk2[0], sA); t1 = __shfl((int)pk3[0], sA);
  a1.x = gh ? (unsigned)t1 : (unsigned)t0;
  t0 = __shfl((int)pk2[1], sA); t1 = __shfl((int)pk3[1], sA);
  a1.y = gh ? (unsigned)t1 : (unsigned)t0;
  t0 = __shfl((int)pk2[0], sB); t1 = __shfl((int)pk3[0], sB);
  a1.z = gh ? (unsigned)t1 : (unsigned)t0;
  t0 = __shfl((int)pk2[1], sB); t1 = __shfl((int)pk3[1], sB);
  a1.w = gh ? (unsigned)t1 : (unsigned)t0;
  pa0o = __builtin_bit_cast(short8, a0);
  pa1o = __builtin_bit_cast(short8, a1);
}

// ---------------- flash attention: 32 q/wave, K+V LDS dbuf, 4-way KV split ----------------
// Mask words fully hoisted before the loop: the loop body has NO per-lane global
// loads, so the only vmem in flight is the async staging (drained at the barrier
// after a full compute phase of cover).
__global__ __launch_bounds__(256, 4) void attn(const unsigned short* __restrict__ qk,
                                               const unsigned short* __restrict__ vT,
                                               const unsigned int* __restrict__ mbits,
                                               unsigned short* __restrict__ po0,
                                               unsigned short* __restrict__ po1,
                                               unsigned short* __restrict__ po2,
                                               unsigned short* __restrict__ po3,
                                               float* __restrict__ pl0,
                                               float* __restrict__ pl1,
                                               float* __restrict__ pl2,
                                               float* __restrict__ pl3) {
  __shared__ __align__(16) unsigned short Ks[2][64 * 64];
  __shared__ __align__(16) unsigned short Vs[2][64 * 64];
  const int tid = threadIdx.x;
  const int w = tid >> 6, l = tid & 63;
  const int b = blockIdx.z, h = blockIdx.y;
  const int qt = blockIdx.x & 15, kvh = blockIdx.x >> 4;   // kvh 0..3
  const int q0 = qt * 128;
  const int kvbase = kvh << 9;                              // 512-wide KV slices
  unsigned short* po = (kvh == 0) ? po0 : (kvh == 1) ? po1 : (kvh == 2) ? po2 : po3;
  float* pl = (kvh == 0) ? pl0 : (kvh == 1) ? pl1 : (kvh == 2) ? pl2 : pl3;
  const int c = l & 15, g = l >> 4;
  const int lr = l >> 3, pg = l & 7;

  // two q-rows per lane: qa (set A) and qb = qa+16 (set B); Q pre-scaled via W_qk
  const int qa = q0 + w * 32 + c;
  const int qb = qa + 16;
  const unsigned short* qptrA = qk + (long)(b * 2048 + qa) * 2048 + h * 128;
  const unsigned short* qptrB = qk + (long)(b * 2048 + qb) * 2048 + h * 128;
  short8 bqA0 = *(const short8*)&qptrA[g * 8];
  short8 bqA1 = *(const short8*)&qptrA[32 + g * 8];
  short8 bqB0 = *(const short8*)&qptrB[g * 8];
  short8 bqB1 = *(const short8*)&qptrB[32 + g * 8];

  const int sw0 = ((g)     ^ (c & 7)) * 8;
  const int sw1 = ((g + 4) ^ (c & 7)) * 8;
  const int sA = c + (((2 * g)     & 3) << 4);
  const int sB = c + (((2 * g + 1) & 3) << 4);
  const int gh = g >> 1;

  // hoist ALL mask words for this wave's 8 KV tiles (64 B per q-row)
  const unsigned int* mwordA = mbits + (long)qa * 64 + (kvbase >> 5);
  const unsigned int* mwordB = mbits + (long)qb * 64 + (kvbase >> 5);
  u32x4 mAw[4], mBw[4];
  #pragma unroll
  for (int j = 0; j < 4; j++) {
    mAw[j] = *(const u32x4*)&mwordA[j * 4];
    mBw[j] = *(const u32x4*)&mwordB[j * 4];
  }

  // staging geometry (slot = w + j*4, row = slot*8 + lr, XOR-swizzled source col)
  const unsigned short* kbase = qk + (long)b * 2048 * 2048 + h * 128 + 64;
  const unsigned short* vbase = vT + (long)((b * 16 + h) * 64) * 2048;
  const int srow = w * 8 + lr;
  const int sgg = pg ^ (lr & 7);

  float lA = 0.f, lB = 0.f;
  f32x4 oA[4], oB[4];
  #pragma unroll
  for (int d = 0; d < 4; d++) { oA[d] = zero4(); oB[d] = zero4(); }

  // prologue: stage K,V tile 0 into buf 0
  #pragma unroll
  for (int j = 0; j < 2; j++) {
    int row = srow + j * 32;
    gl_lds16(kbase + (long)(kvbase + row) * 2048 + sgg * 8, &Ks[0][(w + j * 4) * 512]);
    gl_lds16(vbase + (long)row * 2048 + kvbase + sgg * 8,   &Vs[0][(w + j * 4) * 512]);
  }
  __syncthreads();

  #pragma unroll
  for (int it = 0; it < 8; it++) {
    const int kv0 = kvbase + it * 64;
    const int cur = it & 1;

    // issue next tile's staging (async; in flight across the whole compute phase)
    if (it < 7) {
      #pragma unroll
      for (int j = 0; j < 2; j++) {
        int row = srow + j * 32;
        gl_lds16(kbase + (long)(kv0 + 64 + row) * 2048 + sgg * 8,
                 &Ks[cur ^ 1][(w + j * 4) * 512]);
        gl_lds16(vbase + (long)row * 2048 + kv0 + 64 + sgg * 8,
                 &Vs[cur ^ 1][(w + j * 4) * 512]);
      }
    }

    // mask words from registers (no global load in loop)
    unsigned long long mwA = ((unsigned long long)mAw[it >> 1][(2 * it + 1) & 3] << 32)
                           | mAw[it >> 1][(2 * it) & 3];
    unsigned long long mwB = ((unsigned long long)mBw[it >> 1][(2 * it + 1) & 3] << 32)
                           | mBw[it >> 1][(2 * it) & 3];

    // S^T = K Q^T for both q-sets; K fragments read once from LDS, reused
    f32x4 sfA[4], sfB[4];
    __builtin_amdgcn_s_setprio(1);
    #pragma unroll
    for (int kvq = 0; kvq < 4; kvq++) {
      int R = kvq * 16 + c;
      short8 ak0 = *(const short8*)&Ks[cur][R * 64 + sw0];
      short8 ak1 = *(const short8*)&Ks[cur][R * 64 + sw1];
      f32x4 zA = zero4();
      zA = MFMA16(ak0, bqA0, zA);
      zA = MFMA16(ak1, bqA1, zA);
      sfA[kvq] = zA;
      f32x4 zB = zero4();
      zB = MFMA16(ak0, bqB0, zB);
      zB = MFMA16(ak1, bqB1, zB);
      sfB[kvq] = zB;
    }
    __builtin_amdgcn_s_setprio(0);

    short8 paA0, paA1, paB0, paB1;
    softmax_pack(sfA, mwA, g, sA, sB, gh, lA, paA0, paA1);
    softmax_pack(sfB, mwB, g, sA, sB, gh, lB, paB0, paB1);

    // O += P V ; V fragments read once from LDS, reused across q-sets
    __builtin_amdgcn_s_setprio(1);
    #pragma unroll
    for (int dt = 0; dt < 4; dt++) {
      int d = dt * 16 + c;
      short8 bv0 = *(const short8*)&Vs[cur][d * 64 + sw0];
      short8 bv1 = *(const short8*)&Vs[cur][d * 64 + sw1];
      oA[dt] = MFMA16(paA0, bv0, oA[dt]);
      oA[dt] = MFMA16(paA1, bv1, oA[dt]);
      oB[dt] = MFMA16(paB0, bv0, oB[dt]);
      oB[dt] = MFMA16(paB1, bv1, oB[dt]);
    }
    __builtin_amdgcn_s_setprio(0);

    __syncthreads();
  }

  // l partial reductions + stores for both q-sets
  lA += __shfl_xor(lA, 16); lA += __shfl_xor(lA, 32);
  lB += __shfl_xor(lB, 16); lB += __shfl_xor(lB, 32);
  if (g == 0) {
    pl[((long)(b << 11) + qa) * 16 + h] = lA;
    pl[((long)(b << 11) + qb) * 16 + h] = lB;
  }
  #pragma unroll
  for (int dt = 0; dt < 4; dt++) {
    long rowA = (long)b * 2048 + q0 + w * 32 + g * 4;
    long rowB = rowA + 16;
    int col = h * 64 + dt * 16 + c;
    po[(rowA + 0) * 1024 + col] = f2bf(oA[dt][0]);
    po[(rowA + 1) * 1024 + col] = f2bf(oA[dt][1]);
    po[(rowA + 2) * 1024 + col] = f2bf(oA[dt][2]);
    po[(rowA + 3) * 1024 + col] = f2bf(oA[dt][3]);
    po[(rowB + 0) * 1024 + col] = f2bf(oB[dt][0]);
    po[(rowB + 1) * 1024 + col] = f2bf(oB[dt][1]);
    po[(rowB + 2) * 1024 + col] = f2bf(oB[dt][2]);
    po[(rowB + 3) * 1024 + col] = f2bf(oB[dt][3]);
  }
}

// ---------------- combine 4 KV-split partials: vals = sum(o)/sum(l) ----------------
__global__ __launch_bounds__(256) void combine(const unsigned short* __restrict__ po0,
                                               const unsigned short* __restrict__ po1,
                                               const unsigned short* __restrict__ po2,
                                               const unsigned short* __restrict__ po3,
                                               const float* __restrict__ pl0,
                                               const float* __restrict__ pl1,
                                               const float* __restrict__ pl2,
                                               const float* __restrict__ pl3,
                                               unsigned short* __restrict__ vals) {
  int i = blockIdx.x * 256 + threadIdx.x;   // 0..524287, 8 cols each
  int q = i >> 7;                           // 0..4095 (b*2048+s)
  int col = (i & 127) * 8;
  int h = col >> 6;
  float linv = 1.0f / (pl0[q * 16 + h] + pl1[q * 16 + h] + pl2[q * 16 + h] + pl3[q * 16 + h]);
  long off = (long)q * 1024 + col;
  short8 a = *(const short8*)&po0[off];
  short8 b = *(const short8*)&po1[off];
  short8 cc = *(const short8*)&po2[off];
  short8 d = *(const short8*)&po3[off];
  short8 o;
  #pragma unroll
  for (int j = 0; j < 8; j++) {
    float fa = __builtin_bit_cast(float, ((unsigned int)(unsigned short)a[j]) << 16);
    float fb = __builtin_bit_cast(float, ((unsigned int)(unsigned short)b[j]) << 16);
    float fc = __builtin_bit_cast(float, ((unsigned int)(unsigned short)cc[j]) << 16);
    float fd = __builtin_bit_cast(float, ((unsigned int)(unsigned short)d[j]) << 16);
    o[j] = (short)f2bf((fa + fb + fc + fd) * linv);
  }
  *(short8*)&vals[off] = o;
}

extern "C" void kernel_launch(void* const* d_in, const int* in_sizes, int n_in,
                              void* d_out, int out_size, void* d_ws, size_t ws_size,
                              hipStream_t stream) {
  const float* xe  = (const float*)d_in[0];
  const float* xd  = (const float*)d_in[1];
  const int*   msk = (const int*)d_in[2];
  const float* wqk = (const float*)d_in[3];
  const float* wv  = (const float*)d_in[4];
  const float* wo  = (const float*)d_in[5];
  float* out = (float*)d_out;
  unsigned short* ws = (unsigned short*)d_ws;

  // workspace layout (ushort elements) — same footprint as R7/R8:
  unsigned short* po0    = ws;
  unsigned short* po1    = ws + 4194304;
  float*          pl0    = (float*)(ws + 8388608);
  float*          pl1    = (float*)(ws + 8519680);
  unsigned short* xe_bf  = ws + 8650752;
  unsigned short* xd_bf  = ws + 12845056;
  unsigned short* wqk_bf = ws + 17039360;
  unsigned short* wv_bf  = ws + 19136512;
  unsigned short* wo_bf  = ws + 20185088;
  unsigned short* qkb    = ws + 21233664;
  unsigned short* vTb    = ws + 29622272;
  unsigned short* valb   = ws + 33816576;
  unsigned int*   mbits  = (unsigned int*)(ws + 38010880);
  unsigned short* po2    = xe_bf;                       // dead after gemm_qkv
  unsigned short* po3    = xd_bf;                       // dead after gemm_qkv
  float*          pl2    = (float*)wqk_bf;              // dead after gemm_qkv
  float*          pl3    = (float*)(wqk_bf + 131072);

  prep<<<12800, 256, 0, stream>>>(xe, xd, wqk, wv, wo, msk, mbits, ws);
  gemm_qkv<<<768, 256, 0, stream>>>(xe_bf, xd_bf, wqk_bf, wv_bf, qkb, vTb);
  attn<<<dim3(64, 16, 2), 256, 0, stream>>>(qkb, vTb, mbits,
                                            po0, po1, po2, po3, pl0, pl1, pl2, pl3);
  combine<<<2048, 256, 0, stream>>>(po0, po1, po2, po3, pl0, pl1, pl2, pl3, valb);
  gemm_out<<<dim3(16, 32), 256, 0, stream>>>(valb, wo_bf, out);
}

// Round 10
// 167.729 us; speedup vs baseline: 1.0136x; 1.0109x over previous
//
#include <hip/hip_runtime.h>

typedef __attribute__((ext_vector_type(8))) short short8;
typedef __attribute__((ext_vector_type(4))) float f32x4;
typedef __attribute__((ext_vector_type(4))) unsigned short u16x4;
typedef __attribute__((ext_vector_type(4))) unsigned int u32x4;

#define MFMA16(A,B,C) __builtin_amdgcn_mfma_f32_16x16x32_bf16(A,B,C,0,0,0)

__device__ __forceinline__ unsigned short f2bf(float f) {
  unsigned int u = __builtin_bit_cast(unsigned int, f);
  unsigned int r = (u + 0x7fffu + ((u >> 16) & 1u)) >> 16;
  return (unsigned short)r;
}

__device__ __forceinline__ unsigned int cvt_pk_bf16(float lo, float hi) {
  unsigned int r;
  asm("v_cvt_pk_bf16_f32 %0, %1, %2" : "=v"(r) : "v"(lo), "v"(hi));
  return r;
}

__device__ __forceinline__ f32x4 zero4() {
  f32x4 z; z.x = 0.f; z.y = 0.f; z.z = 0.f; z.w = 0.f; return z;
}

__device__ __forceinline__ void gl_lds16(const void* g, void* l) {
  __builtin_amdgcn_global_load_lds((const __attribute__((address_space(1))) void*)g,
                                   (__attribute__((address_space(3))) void*)l, 16, 0, 0);
}

// ---------------- prep: f32->bf16 converts + mask bit-pack, one dispatch ----------------
// W_qk q-projection rows pre-scaled by (1/sqrt(hd))*log2(e) -> attn uses exp2 directly.
__global__ __launch_bounds__(256) void prep(const float* __restrict__ xe,
                                            const float* __restrict__ xd,
                                            const float* __restrict__ wqk,
                                            const float* __restrict__ wv,
                                            const float* __restrict__ wo,
                                            const int* __restrict__ mask,
                                            unsigned int* __restrict__ mbits,
                                            unsigned short* __restrict__ ws) {
  if (blockIdx.x >= 12288) {
    int idx = (blockIdx.x - 12288) * 256 + threadIdx.x;   // word index 0..131071
    int row = idx >> 6, wi = idx & 63;
    const int* p = mask + (long)row * 2048 + wi * 32;
    unsigned int bits = 0;
    #pragma unroll
    for (int j = 0; j < 32; j++) bits |= (p[j] != 0 ? 1u : 0u) << j;
    mbits[idx] = bits;
    return;
  }
  long i = (long)blockIdx.x * 256 + threadIdx.x;  // float4 index
  const float* src; unsigned short* dst; long o; bool scl = false;
  if (i < 1048576)      { src = xe;  dst = ws + 8650752;  o = i; }            // xe_bf
  else if (i < 2097152) { src = xd;  dst = ws + 12845056; o = i - 1048576; }  // xd_bf
  else if (i < 2621440) { src = wqk; dst = ws + 17039360; o = i - 2097152;    // wqk_bf
                          scl = (((o >> 8) & 127) < 64); }                    // q rows
  else if (i < 2883584) { src = wv;  dst = ws + 19136512; o = i - 2621440; }  // wv_bf
  else                  { src = wo;  dst = ws + 20185088; o = i - 2883584; }  // wo_bf
  float4 f = ((const float4*)src)[o];
  if (scl) {
    const float SCQ = 0.125f * 1.4426950408889634f;
    f.x *= SCQ; f.y *= SCQ; f.z *= SCQ; f.w *= SCQ;
  }
  u16x4 r; r.x = f2bf(f.x); r.y = f2bf(f.y); r.z = f2bf(f.z); r.w = f2bf(f.w);
  ((u16x4*)dst)[o] = r;
}

// ---------------- fused QK+V GEMM: 768 blocks, K=1024, XCD-aware block decode ----------------
__global__ __launch_bounds__(256) void gemm_qkv(const unsigned short* __restrict__ xe,
                                                const unsigned short* __restrict__ xd,
                                                const unsigned short* __restrict__ wqk,
                                                const unsigned short* __restrict__ wv,
                                                unsigned short* __restrict__ qkb,
                                                unsigned short* __restrict__ vTb) {
  __shared__ __align__(16) unsigned short As[128 * 64];
  __shared__ __align__(16) unsigned short Bs[128 * 64];
  const int bid = blockIdx.x;
  const unsigned short* A; const unsigned short* B;
  long row0, col0; int mode;
  // XCD-aware decode: blocks sharing an A row-panel land on one XCD (xcd = bid&7)
  if (bid < 512) {
    int xcd = bid & 7, j = bid >> 3;          // j 0..63
    A = xe; B = wqk; mode = 0;
    row0 = (long)(xcd * 4 + (j >> 4)) * 128;  // 32 rows
    col0 = (long)(j & 15) * 128;              // 16 cols
  } else {
    int p = bid - 512;
    int xcd = p & 7, j = p >> 3;              // j 0..31
    A = xd; B = wv; mode = 1;
    row0 = (long)(xcd * 4 + (j >> 3)) * 128;  // 32 rows
    col0 = (long)(j & 7) * 128;               // 8 cols
  }

  const int tid = threadIdx.x;
  const int w = tid >> 6, l = tid & 63;
  const int wr = w >> 1, wc = w & 1;
  const int lr = l >> 3;
  const int lc = (l & 7) * 8;

  f32x4 acc[4][4];
  #pragma unroll
  for (int m = 0; m < 4; m++)
    #pragma unroll
    for (int n = 0; n < 4; n++) acc[m][n] = zero4();

  for (int k0 = 0; k0 < 1024; k0 += 64) {
    #pragma unroll
    for (int j = 0; j < 4; j++) {
      int slot = j * 4 + w;
      int row = slot * 8 + lr;
      gl_lds16(A + (row0 + row) * 1024 + k0 + lc, &As[slot * 512]);
      gl_lds16(B + (col0 + row) * 1024 + k0 + lc, &Bs[slot * 512]);
    }
    __syncthreads();
    #pragma unroll
    for (int kk = 0; kk < 2; kk++) {
      short8 a[4], b[4];
      #pragma unroll
      for (int m = 0; m < 4; m++)
        a[m] = *(const short8*)&As[(wr * 64 + m * 16 + (l & 15)) * 64 + kk * 32 + (l >> 4) * 8];
      #pragma unroll
      for (int n = 0; n < 4; n++)
        b[n] = *(const short8*)&Bs[(wc * 64 + n * 16 + (l & 15)) * 64 + kk * 32 + (l >> 4) * 8];
      #pragma unroll
      for (int m = 0; m < 4; m++)
        #pragma unroll
        for (int n = 0; n < 4; n++)
          acc[m][n] = MFMA16(a[m], b[n], acc[m][n]);
    }
    __syncthreads();
  }

  #pragma unroll
  for (int m = 0; m < 4; m++) {
    long rowb = row0 + wr * 64 + m * 16 + ((l >> 4) * 4);
    #pragma unroll
    for (int n = 0; n < 4; n++) {
      long colb = col0 + wc * 64 + n * 16 + (l & 15);
      if (mode == 0) {
        #pragma unroll
        for (int r = 0; r < 4; r++) qkb[(rowb + r) * 2048 + colb] = f2bf(acc[m][n][r]);
      } else {
        long bb = rowb >> 11, s0 = rowb & 2047;
        u16x4 pk;
        pk.x = f2bf(acc[m][n][0]); pk.y = f2bf(acc[m][n][1]);
        pk.z = f2bf(acc[m][n][2]); pk.w = f2bf(acc[m][n][3]);
        *(u16x4*)&vTb[(bb * 1024 + colb) * 2048 + s0] = pk;
      }
    }
  }
}

// ---------------- final GEMM: out = vals @ W_o^T, f32, 128x64 tiles, XCD decode ----------------
__global__ __launch_bounds__(256) void gemm_out(const unsigned short* __restrict__ A,
                                                const unsigned short* __restrict__ B,
                                                float* __restrict__ C) {
  __shared__ __align__(16) unsigned short As[128 * 64];
  __shared__ __align__(16) unsigned short Bs[64 * 64];
  const int i = blockIdx.x;                 // 512 blocks
  const int xcd = i & 7, j = i >> 3;        // j 0..63
  const long row0 = (long)(xcd * 4 + (j >> 4)) * 128;  // 32 rows
  const long col0 = (long)(j & 15) * 64;               // 16 cols
  const int tid = threadIdx.x;
  const int w = tid >> 6, l = tid & 63;
  const int wr = w >> 1, wc = w & 1;
  const int lr = l >> 3;
  const int lc = (l & 7) * 8;

  f32x4 acc[4][2];
  #pragma unroll
  for (int m = 0; m < 4; m++)
    #pragma unroll
    for (int n = 0; n < 2; n++) acc[m][n] = zero4();

  for (int k0 = 0; k0 < 1024; k0 += 64) {
    #pragma unroll
    for (int jj = 0; jj < 4; jj++) {
      int slot = jj * 4 + w;
      int row = slot * 8 + lr;
      gl_lds16(A + (row0 + row) * 1024 + k0 + lc, &As[slot * 512]);
    }
    #pragma unroll
    for (int jj = 0; jj < 2; jj++) {
      int slot = jj * 4 + w;
      int row = slot * 8 + lr;
      gl_lds16(B + (col0 + row) * 1024 + k0 + lc, &Bs[slot * 512]);
    }
    __syncthreads();
    #pragma unroll
    for (int kk = 0; kk < 2; kk++) {
      short8 a[4], b[2];
      #pragma unroll
      for (int m = 0; m < 4; m++)
        a[m] = *(const short8*)&As[(wr * 64 + m * 16 + (l & 15)) * 64 + kk * 32 + (l >> 4) * 8];
      #pragma unroll
      for (int n = 0; n < 2; n++)
        b[n] = *(const short8*)&Bs[(wc * 32 + n * 16 + (l & 15)) * 64 + kk * 32 + (l >> 4) * 8];
      #pragma unroll
      for (int m = 0; m < 4; m++)
        #pragma unroll
        for (int n = 0; n < 2; n++)
          acc[m][n] = MFMA16(a[m], b[n], acc[m][n]);
    }
    __syncthreads();
  }

  #pragma unroll
  for (int m = 0; m < 4; m++) {
    long rowb = row0 + wr * 64 + m * 16 + ((l >> 4) * 4);
    #pragma unroll
    for (int n = 0; n < 2; n++) {
      long colb = col0 + wc * 32 + n * 16 + (l & 15);
      #pragma unroll
      for (int r = 0; r < 4; r++) C[(rowb + r) * 1024 + colb] = acc[m][n][r];
    }
  }
}

// ---------------- softmax (exp2-direct, masked) + pack + redistribute ----------------
__device__ __forceinline__ void softmax_pack(const f32x4* sf, unsigned long long mw,
                                             int g, int sA, int sB, int gh,
                                             float& l_run, short8& pa0o, short8& pa1o) {
  mw >>= (g * 4);
  unsigned int mlo = (unsigned int)mw, mhi = (unsigned int)(mw >> 32);
  float pv[16];
  float lsum = 0.f;
  #pragma unroll
  for (int kvq = 0; kvq < 4; kvq++) {
    unsigned int msel = (kvq < 2) ? mlo : mhi;
    #pragma unroll
    for (int r = 0; r < 4; r++) {
      float e = __builtin_amdgcn_exp2f(sf[kvq][r]);   // scale pre-folded into W_qk
      unsigned int bit = (msel >> (((kvq & 1) << 4) + r)) & 1u;
      float p = bit ? e : 0.0f;
      pv[kvq * 4 + r] = p;
      lsum += p;
    }
  }
  l_run += lsum;

  unsigned int pk0[2], pk1[2], pk2[2], pk3[2];
  pk0[0] = cvt_pk_bf16(pv[0],  pv[1]);  pk0[1] = cvt_pk_bf16(pv[2],  pv[3]);
  pk1[0] = cvt_pk_bf16(pv[4],  pv[5]);  pk1[1] = cvt_pk_bf16(pv[6],  pv[7]);
  pk2[0] = cvt_pk_bf16(pv[8],  pv[9]);  pk2[1] = cvt_pk_bf16(pv[10], pv[11]);
  pk3[0] = cvt_pk_bf16(pv[12], pv[13]); pk3[1] = cvt_pk_bf16(pv[14], pv[15]);

  u32x4 a0, a1;
  int t0, t1;
  t0 = __shfl((int)pk0[0], sA); t1 = __shfl((int)pk1[0], sA);
  a0.x = gh ? (unsigned)t1 : (unsigned)t0;
  t0 = __shfl((int)pk0[1], sA); t1 = __shfl((int)pk1[1], sA);
  a0.y = gh ? (unsigned)t1 : (unsigned)t0;
  t0 = __shfl((int)pk0[0], sB); t1 = __shfl((int)pk1[0], sB);
  a0.z = gh ? (unsigned)t1 : (unsigned)t0;
  t0 = __shfl((int)pk0[1], sB); t1 = __shfl((int)pk1[1], sB);
  a0.w = gh ? (unsigned)t1 : (unsigned)t0;
  t0 = __shfl((int)pk2[0], sA); t1 = __shfl((int)pk3[0], sA);
  a1.x = gh ? (unsigned)t1 : (unsigned)t0;
  t0 = __shfl((int)pk2[1], sA); t1 = __shfl((int)pk3[1], sA);
  a1.y = gh ? (unsigned)t1 : (unsigned)t0;
  t0 = __shfl((int)pk2[0], sB); t1 = __shfl((int)pk3[0], sB);
  a1.z = gh ? (unsigned)t1 : (unsigned)t0;
  t0 = __shfl((int)pk2[1], sB); t1 = __shfl((int)pk3[1], sB);
  a1.w = gh ? (unsigned)t1 : (unsigned)t0;
  pa0o = __builtin_bit_cast(short8, a0);
  pa1o = __builtin_bit_cast(short8, a1);
}

// ---------------- flash attention: 32 q/wave, K+V LDS dbuf, 4-way KV split ----------------
// XCD-aware 1-D grid decode: the 16 qt-blocks sharing one (b,h,kvh) K/V slice all
// land on the same XCD (xcd = blockIdx&7) -> slice fetched once per XCD L2, not 8x.
__global__ __launch_bounds__(256, 4) void attn(const unsigned short* __restrict__ qk,
                                               const unsigned short* __restrict__ vT,
                                               const unsigned int* __restrict__ mbits,
                                               unsigned short* __restrict__ po0,
                                               unsigned short* __restrict__ po1,
                                               unsigned short* __restrict__ po2,
                                               unsigned short* __restrict__ po3,
                                               float* __restrict__ pl0,
                                               float* __restrict__ pl1,
                                               float* __restrict__ pl2,
                                               float* __restrict__ pl3) {
  __shared__ __align__(16) unsigned short Ks[2][64 * 64];
  __shared__ __align__(16) unsigned short Vs[2][64 * 64];
  const int tid = threadIdx.x;
  const int w = tid >> 6, l = tid & 63;
  // XCD decode: i -> (b, h, kvh, qt) with qt innermost per XCD
  const int i = blockIdx.x;                 // 0..2047
  const int xcd = i & 7, jj = i >> 3;       // jj 0..255
  const int grp = xcd * 16 + (jj >> 4);     // 0..127 = (b,h,kvh) group
  const int qt = jj & 15;
  const int kvh = grp & 3;
  const int h = (grp >> 2) & 15;
  const int b = grp >> 6;
  const int q0 = qt * 128;
  const int kvbase = kvh << 9;              // 512-wide KV slices
  unsigned short* po = (kvh == 0) ? po0 : (kvh == 1) ? po1 : (kvh == 2) ? po2 : po3;
  float* pl = (kvh == 0) ? pl0 : (kvh == 1) ? pl1 : (kvh == 2) ? pl2 : pl3;
  const int c = l & 15, g = l >> 4;
  const int lr = l >> 3, pg = l & 7;

  // two q-rows per lane: qa (set A) and qb = qa+16 (set B); Q pre-scaled via W_qk
  const int qa = q0 + w * 32 + c;
  const int qb = qa + 16;
  const unsigned short* qptrA = qk + (long)(b * 2048 + qa) * 2048 + h * 128;
  const unsigned short* qptrB = qk + (long)(b * 2048 + qb) * 2048 + h * 128;
  short8 bqA0 = *(const short8*)&qptrA[g * 8];
  short8 bqA1 = *(const short8*)&qptrA[32 + g * 8];
  short8 bqB0 = *(const short8*)&qptrB[g * 8];
  short8 bqB1 = *(const short8*)&qptrB[32 + g * 8];

  const int sw0 = ((g)     ^ (c & 7)) * 8;
  const int sw1 = ((g + 4) ^ (c & 7)) * 8;
  const int sA = c + (((2 * g)     & 3) << 4);
  const int sB = c + (((2 * g + 1) & 3) << 4);
  const int gh = g >> 1;

  const unsigned int* mrowA = mbits + (long)qa * 64;
  const unsigned int* mrowB = mbits + (long)qb * 64;

  // staging geometry (slot = w + j*4, row = slot*8 + lr, XOR-swizzled source col)
  const unsigned short* kbase = qk + (long)b * 2048 * 2048 + h * 128 + 64;
  const unsigned short* vbase = vT + (long)((b * 16 + h) * 64) * 2048;
  const int srow = w * 8 + lr;
  const int sgg = pg ^ (lr & 7);

  float lA = 0.f, lB = 0.f;
  f32x4 oA[4], oB[4];
  #pragma unroll
  for (int d = 0; d < 4; d++) { oA[d] = zero4(); oB[d] = zero4(); }

  // prologue: stage K,V tile 0 into buf 0
  #pragma unroll
  for (int j = 0; j < 2; j++) {
    int row = srow + j * 32;
    gl_lds16(kbase + (long)(kvbase + row) * 2048 + sgg * 8, &Ks[0][(w + j * 4) * 512]);
    gl_lds16(vbase + (long)row * 2048 + kvbase + sgg * 8,   &Vs[0][(w + j * 4) * 512]);
  }
  __syncthreads();

  for (int it = 0; it < 8; it++) {
    const int kv0 = kvbase + it * 64;
    const int cur = it & 1;

    // issue next tile's staging (async, drained by the end-of-iter barrier)
    if (it < 7) {
      #pragma unroll
      for (int j = 0; j < 2; j++) {
        int row = srow + j * 32;
        gl_lds16(kbase + (long)(kv0 + 64 + row) * 2048 + sgg * 8,
                 &Ks[cur ^ 1][(w + j * 4) * 512]);
        gl_lds16(vbase + (long)row * 2048 + kv0 + 64 + sgg * 8,
                 &Vs[cur ^ 1][(w + j * 4) * 512]);
      }
    }

    unsigned long long mwA = *(const unsigned long long*)&mrowA[kv0 >> 5];
    unsigned long long mwB = *(const unsigned long long*)&mrowB[kv0 >> 5];

    // S^T = K Q^T for both q-sets; K fragments read once from LDS, reused
    f32x4 sfA[4], sfB[4];
    #pragma unroll
    for (int kvq = 0; kvq < 4; kvq++) {
      int R = kvq * 16 + c;
      short8 ak0 = *(const short8*)&Ks[cur][R * 64 + sw0];
      short8 ak1 = *(const short8*)&Ks[cur][R * 64 + sw1];
      f32x4 zA = zero4();
      zA = MFMA16(ak0, bqA0, zA);
      zA = MFMA16(ak1, bqA1, zA);
      sfA[kvq] = zA;
      f32x4 zB = zero4();
      zB = MFMA16(ak0, bqB0, zB);
      zB = MFMA16(ak1, bqB1, zB);
      sfB[kvq] = zB;
    }

    short8 paA0, paA1, paB0, paB1;
    softmax_pack(sfA, mwA, g, sA, sB, gh, lA, paA0, paA1);
    softmax_pack(sfB, mwB, g, sA, sB, gh, lB, paB0, paB1);

    // O += P V ; V fragments read once from LDS, reused across q-sets
    #pragma unroll
    for (int dt = 0; dt < 4; dt++) {
      int d = dt * 16 + c;
      short8 bv0 = *(const short8*)&Vs[cur][d * 64 + sw0];
      short8 bv1 = *(const short8*)&Vs[cur][d * 64 + sw1];
      oA[dt] = MFMA16(paA0, bv0, oA[dt]);
      oA[dt] = MFMA16(paA1, bv1, oA[dt]);
      oB[dt] = MFMA16(paB0, bv0, oB[dt]);
      oB[dt] = MFMA16(paB1, bv1, oB[dt]);
    }

    __syncthreads();
  }

  // l partial reductions + stores for both q-sets
  lA += __shfl_xor(lA, 16); lA += __shfl_xor(lA, 32);
  lB += __shfl_xor(lB, 16); lB += __shfl_xor(lB, 32);
  if (g == 0) {
    pl[((long)(b << 11) + qa) * 16 + h] = lA;
    pl[((long)(b << 11) + qb) * 16 + h] = lB;
  }
  #pragma unroll
  for (int dt = 0; dt < 4; dt++) {
    long rowA = (long)b * 2048 + q0 + w * 32 + g * 4;
    long rowB = rowA + 16;
    int col = h * 64 + dt * 16 + c;
    po[(rowA + 0) * 1024 + col] = f2bf(oA[dt][0]);
    po[(rowA + 1) * 1024 + col] = f2bf(oA[dt][1]);
    po[(rowA + 2) * 1024 + col] = f2bf(oA[dt][2]);
    po[(rowA + 3) * 1024 + col] = f2bf(oA[dt][3]);
    po[(rowB + 0) * 1024 + col] = f2bf(oB[dt][0]);
    po[(rowB + 1) * 1024 + col] = f2bf(oB[dt][1]);
    po[(rowB + 2) * 1024 + col] = f2bf(oB[dt][2]);
    po[(rowB + 3) * 1024 + col] = f2bf(oB[dt][3]);
  }
}

// ---------------- combine 4 KV-split partials: vals = sum(o)/sum(l) ----------------
__global__ __launch_bounds__(256) void combine(const unsigned short* __restrict__ po0,
                                               const unsigned short* __restrict__ po1,
                                               const unsigned short* __restrict__ po2,
                                               const unsigned short* __restrict__ po3,
                                               const float* __restrict__ pl0,
                                               const float* __restrict__ pl1,
                                               const float* __restrict__ pl2,
                                               const float* __restrict__ pl3,
                                               unsigned short* __restrict__ vals) {
  int i = blockIdx.x * 256 + threadIdx.x;   // 0..524287, 8 cols each
  int q = i >> 7;                           // 0..4095 (b*2048+s)
  int col = (i & 127) * 8;
  int h = col >> 6;
  float linv = 1.0f / (pl0[q * 16 + h] + pl1[q * 16 + h] + pl2[q * 16 + h] + pl3[q * 16 + h]);
  long off = (long)q * 1024 + col;
  short8 a = *(const short8*)&po0[off];
  short8 b = *(const short8*)&po1[off];
  short8 cc = *(const short8*)&po2[off];
  short8 d = *(const short8*)&po3[off];
  short8 o;
  #pragma unroll
  for (int j = 0; j < 8; j++) {
    float fa = __builtin_bit_cast(float, ((unsigned int)(unsigned short)a[j]) << 16);
    float fb = __builtin_bit_cast(float, ((unsigned int)(unsigned short)b[j]) << 16);
    float fc = __builtin_bit_cast(float, ((unsigned int)(unsigned short)cc[j]) << 16);
    float fd = __builtin_bit_cast(float, ((unsigned int)(unsigned short)d[j]) << 16);
    o[j] = (short)f2bf((fa + fb + fc + fd) * linv);
  }
  *(short8*)&vals[off] = o;
}

extern "C" void kernel_launch(void* const* d_in, const int* in_sizes, int n_in,
                              void* d_out, int out_size, void* d_ws, size_t ws_size,
                              hipStream_t stream) {
  const float* xe  = (const float*)d_in[0];
  const float* xd  = (const float*)d_in[1];
  const int*   msk = (const int*)d_in[2];
  const float* wqk = (const float*)d_in[3];
  const float* wv  = (const float*)d_in[4];
  const float* wo  = (const float*)d_in[5];
  float* out = (float*)d_out;
  unsigned short* ws = (unsigned short*)d_ws;

  // workspace layout (ushort elements) — same footprint as R7-R9:
  unsigned short* po0    = ws;
  unsigned short* po1    = ws + 4194304;
  float*          pl0    = (float*)(ws + 8388608);
  float*          pl1    = (float*)(ws + 8519680);
  unsigned short* xe_bf  = ws + 8650752;
  unsigned short* xd_bf  = ws + 12845056;
  unsigned short* wqk_bf = ws + 17039360;
  unsigned short* wv_bf  = ws + 19136512;
  unsigned short* wo_bf  = ws + 20185088;
  unsigned short* qkb    = ws + 21233664;
  unsigned short* vTb    = ws + 29622272;
  unsigned short* valb   = ws + 33816576;
  unsigned int*   mbits  = (unsigned int*)(ws + 38010880);
  unsigned short* po2    = xe_bf;                       // dead after gemm_qkv
  unsigned short* po3    = xd_bf;                       // dead after gemm_qkv
  float*          pl2    = (float*)wqk_bf;              // dead after gemm_qkv
  float*          pl3    = (float*)(wqk_bf + 131072);

  prep<<<12800, 256, 0, stream>>>(xe, xd, wqk, wv, wo, msk, mbits, ws);
  gemm_qkv<<<768, 256, 0, stream>>>(xe_bf, xd_bf, wqk_bf, wv_bf, qkb, vTb);
  attn<<<2048, 256, 0, stream>>>(qkb, vTb, mbits,
                                 po0, po1, po2, po3, pl0, pl1, pl2, pl3);
  combine<<<2048, 256, 0, stream>>>(po0, po1, po2, po3, pl0, pl1, pl2, pl3, valb);
  gemm_out<<<512, 256, 0, stream>>>(valb, wo_bf, out);
}